// Round 10
// baseline (148.700 us; speedup 1.0000x reference)
//
#include <hip/hip_runtime.h>

// BottleneckAdapter: out = residual + Wup·( swish(Wl1·n+bl1) * (Wl2·n+bl2) ),
// n = LN( (Wdown·Wproj)·x ).  W_comb = Wdown@Wproj precomputed per-launch.
// Dims: B=16 S=2048 C=768 Q=1024 D=64 -> ROWS=32768.
//
// R10: decisive TLP probe. Up-GEMM moved INTO k_act (LDS bounce -> contiguous
// dump). Final kernel is a pure m13-style grid-stride elementwise streamer
// (no MFMA/LDS/barriers, tiny VGPR -> max occupancy):
//   ws big enough : k_act dumps bf16 up to ws; k_add_bf16: out = res + up.
//   ws too small  : k_act dumps f32 up to d_out; k_add_f32: out += res (in place,
//                   element-wise => no cross-thread hazard).

#define CDIM 768
#define QDIM 1024

typedef __attribute__((ext_vector_type(8))) short bf16x8;
typedef __attribute__((ext_vector_type(4))) float f32x4;

__device__ __forceinline__ ushort f2bf(float f) {
  union { float f; unsigned u; } v; v.f = f;
  unsigned r = v.u + 0x7fffu + ((v.u >> 16) & 1u);   // RNE
  return (ushort)(r >> 16);
}
__device__ __forceinline__ float bf2f(ushort u) {
  union { float f; unsigned v; } x; x.v = (unsigned)u << 16; return x.f;
}

// ---- K1: partial W_comb, 8 q-chunks. part[qc][c][d] (8 x 768 x 64 f32)
__global__ void k_wcomb(const float* __restrict__ Wproj, const float* __restrict__ Wdown,
                        float* __restrict__ part) {
  int bid = blockIdx.x;                 // 768 = 12 cb * 8 db * 8 qc
  int cb = bid % 12, db = (bid / 12) % 8, qc = bid / 96;
  int l = threadIdx.x;                  // 64
  int c = cb * 64 + l;
  float acc[8];
  #pragma unroll
  for (int i = 0; i < 8; ++i) acc[i] = 0.f;
  int q0 = qc * 128;
  for (int q = q0; q < q0 + 128; ++q) {
    float xp = Wproj[q * CDIM + c];
    #pragma unroll
    for (int i = 0; i < 8; ++i)
      acc[i] = fmaf(Wdown[(db * 8 + i) * QDIM + q], xp, acc[i]);
  }
  #pragma unroll
  for (int i = 0; i < 8; ++i)
    part[((size_t)qc * CDIM + c) * 64 + db * 8 + i] = acc[i];
}

// ---- K2: sum partials + arrange weights into MFMA fragment order (bf16).
// element (lane l, j) of tile (ks,nf) = M[16*nf+(l&15)][32*ks + 8*(l>>4)+j]
__global__ void k_arrange(const float* __restrict__ part, const float* __restrict__ Wup,
                          const float* __restrict__ Wl1, const float* __restrict__ Wl2,
                          ushort* __restrict__ wcf, ushort* __restrict__ wupf,
                          ushort* __restrict__ wl1f, ushort* __restrict__ wl2f) {
  int idx = blockIdx.x * 256 + threadIdx.x;      // 480*256 = 122880
  if (idx < 49152) {                             // wcf
    int i0 = idx;
    int j = i0 & 7, l = (i0 >> 3) & 63, t = i0 >> 9;
    int g = l >> 4, r16 = l & 15;
    int nf = t & 3, ks = t >> 2;
    int k = 32 * ks + 8 * g + j, n = 16 * nf + r16;
    float s = 0.f;
    #pragma unroll
    for (int qc = 0; qc < 8; ++qc) s += part[((size_t)qc * CDIM + k) * 64 + n];
    wcf[i0] = f2bf(s);
  } else if (idx < 49152 + 65536) {              // wupf
    int i2 = idx - 49152;
    int j = i2 & 7, l = (i2 >> 3) & 63, t = i2 >> 9;
    int g = l >> 4, r16 = l & 15;
    int ks = t & 1, nf = t >> 1;
    int k = 32 * ks + 8 * g + j, n = 16 * nf + r16;
    wupf[i2] = f2bf(Wup[n * 64 + k]);
  } else if (idx < 49152 + 65536 + 4096) {       // wl1f
    int i3 = idx - (49152 + 65536);
    int j = i3 & 7, l = (i3 >> 3) & 63, t = i3 >> 9;
    int g = l >> 4, r16 = l & 15;
    int nf = t & 3, ks = t >> 2;
    int k = 32 * ks + 8 * g + j, e = 16 * nf + r16;
    wl1f[i3] = f2bf(Wl1[e * 64 + k]);
  } else {                                       // wl2f
    int i4 = idx - (49152 + 65536 + 4096);
    int j = i4 & 7, l = (i4 >> 3) & 63, t = i4 >> 9;
    int g = l >> 4, r16 = l & 15;
    int nf = t & 3, ks = t >> 2;
    int k = 32 * ks + 8 * g + j, e = 16 * nf + r16;
    wl2f[i4] = f2bf(Wl2[e * 64 + k]);
  }
}

// ---- K_ACT: x -> down -> LN -> SwiGLU -> up-GEMM -> contiguous dump.
// MODE 1: dump bf16 up to upb[row][col].  MODE 0: dump f32 up to outg[row][col].
// LDS union 24832B: x[16][776]us | d[16][68]f32 @0 | n[16][72]us @4608 |
//                   a[16][72]us @22528 | bounce[16][520]us @0 (phase E)
template<int MODE>
__global__ __launch_bounds__(256, 6)
void k_act(const float* __restrict__ xg,
           const float* __restrict__ gamma, const float* __restrict__ beta,
           const float* __restrict__ bl1, const float* __restrict__ bl2,
           const ushort* __restrict__ wcf, const ushort* __restrict__ wupf,
           const ushort* __restrict__ wl1f, const ushort* __restrict__ wl2f,
           ushort* __restrict__ upb, float* __restrict__ outg) {
  __shared__ alignas(16) ushort smem[12416];     // 24832 B
  ushort (*x_lds)[776]  = reinterpret_cast<ushort(*)[776]>(smem);
  float  (*d_lds)[68]   = reinterpret_cast<float (*)[68]>(smem);
  ushort (*n_lds)[72]   = reinterpret_cast<ushort(*)[72]>(reinterpret_cast<char*>(smem) + 4608);
  ushort (*a_lds)[72]   = reinterpret_cast<ushort(*)[72]>(reinterpret_cast<char*>(smem) + 22528);
  ushort (*bounce)[520] = reinterpret_cast<ushort(*)[520]>(smem);

  const int tid = threadIdx.x;
  const int w = tid >> 6, l = tid & 63, g = l >> 4, r16 = l & 15;
  const int row0 = blockIdx.x * 16;

  // Phase A: stage x (16x768 f32) -> LDS bf16, float4 coalesced.
  #pragma unroll
  for (int i = 0; i < 12; ++i) {
    int f4 = i * 256 + tid;
    int r = f4 / 192;
    int c4 = (f4 - r * 192) * 4;
    const float4 v = *reinterpret_cast<const float4*>(xg + (size_t)(row0 + r) * CDIM + c4);
    ushort4 b;
    b.x = f2bf(v.x); b.y = f2bf(v.y); b.z = f2bf(v.z); b.w = f2bf(v.w);
    *reinterpret_cast<ushort4*>(&x_lds[r][c4]) = b;
  }
  __syncthreads();

  // Phase B: d = x * Wcomb^T.
  f32x4 dacc = {0.f, 0.f, 0.f, 0.f};
  #pragma unroll 8
  for (int ks = 0; ks < 24; ++ks) {
    bf16x8 a = *reinterpret_cast<const bf16x8*>(&x_lds[r16][ks * 32 + 8 * g]);
    bf16x8 b = *reinterpret_cast<const bf16x8*>(wcf + ((size_t)(ks * 4 + w) * 64 + l) * 8);
    dacc = __builtin_amdgcn_mfma_f32_16x16x32_bf16(a, b, dacc, 0, 0, 0);
  }
  __syncthreads();
  #pragma unroll
  for (int rg = 0; rg < 4; ++rg) d_lds[4 * g + rg][16 * w + r16] = dacc[rg];
  __syncthreads();

  // Phase C: LayerNorm over D=64.
  {
    int row = 4 * w + g;
    f32x4 v = *reinterpret_cast<const f32x4*>(&d_lds[row][4 * r16]);
    float s  = v[0] + v[1] + v[2] + v[3];
    float sq = v[0]*v[0] + v[1]*v[1] + v[2]*v[2] + v[3]*v[3];
    #pragma unroll
    for (int m = 1; m < 16; m <<= 1) {
      s  += __shfl_xor(s, m, 64);
      sq += __shfl_xor(sq, m, 64);
    }
    float mu  = s * (1.f / 64.f);
    float var = sq * (1.f / 64.f) - mu * mu;
    float rs  = rsqrtf(var + 1e-5f);
    const float4 gm = *reinterpret_cast<const float4*>(gamma + 4 * r16);
    const float4 bt = *reinterpret_cast<const float4*>(beta  + 4 * r16);
    ushort4 nb;
    nb.x = f2bf((v[0] - mu) * rs * gm.x + bt.x);
    nb.y = f2bf((v[1] - mu) * rs * gm.y + bt.y);
    nb.z = f2bf((v[2] - mu) * rs * gm.z + bt.z);
    nb.w = f2bf((v[3] - mu) * rs * gm.w + bt.w);
    *reinterpret_cast<ushort4*>(&n_lds[row][4 * r16]) = nb;
  }
  __syncthreads();

  // Phase D: SwiGLU -> a_lds (@22528, clear of bounce).
  {
    bf16x8 a0 = *reinterpret_cast<const bf16x8*>(&n_lds[r16][8 * g]);
    bf16x8 a1 = *reinterpret_cast<const bf16x8*>(&n_lds[r16][32 + 8 * g]);
    bf16x8 b10 = *reinterpret_cast<const bf16x8*>(wl1f + ((size_t)(0 * 4 + w) * 64 + l) * 8);
    bf16x8 b11 = *reinterpret_cast<const bf16x8*>(wl1f + ((size_t)(1 * 4 + w) * 64 + l) * 8);
    bf16x8 b20 = *reinterpret_cast<const bf16x8*>(wl2f + ((size_t)(0 * 4 + w) * 64 + l) * 8);
    bf16x8 b21 = *reinterpret_cast<const bf16x8*>(wl2f + ((size_t)(1 * 4 + w) * 64 + l) * 8);
    f32x4 z = {0.f, 0.f, 0.f, 0.f};
    f32x4 acc1 = __builtin_amdgcn_mfma_f32_16x16x32_bf16(a0, b10, z, 0, 0, 0);
    acc1 = __builtin_amdgcn_mfma_f32_16x16x32_bf16(a1, b11, acc1, 0, 0, 0);
    f32x4 acc2 = __builtin_amdgcn_mfma_f32_16x16x32_bf16(a0, b20, z, 0, 0, 0);
    acc2 = __builtin_amdgcn_mfma_f32_16x16x32_bf16(a1, b21, acc2, 0, 0, 0);
    float bv1 = bl1[16 * w + r16];
    float bv2 = bl2[16 * w + r16];
    #pragma unroll
    for (int rg = 0; rg < 4; ++rg) {
      float o1 = acc1[rg] + bv1;
      float o2 = acc2[rg] + bv2;
      float sw = o1 / (1.f + __expf(-o1));       // swish
      a_lds[4 * g + rg][16 * w + r16] = f2bf(sw * o2);
    }
  }
  __syncthreads();

  // Phase E: up-GEMM (swapped operands) -> bf16 bounce -> contiguous dump.
  // Lane l: rows r16, cols 16*nf+4g+{0..3}. Two 512-col passes.
  {
    const bf16x8 af0 = *reinterpret_cast<const bf16x8*>(&a_lds[r16][8 * g]);
    const bf16x8 af1 = *reinterpret_cast<const bf16x8*>(&a_lds[r16][32 + 8 * g]);
    #pragma unroll
    for (int p = 0; p < 2; ++p) {
      if (p) __syncthreads();               // prior dump reads complete
      #pragma unroll
      for (int i = 0; i < 8; ++i) {
        size_t nf = 32 * p + 8 * w + i;
        bf16x8 b0 = *reinterpret_cast<const bf16x8*>(wupf + ((nf * 2 + 0) * 64 + l) * 8);
        bf16x8 b1 = *reinterpret_cast<const bf16x8*>(wupf + ((nf * 2 + 1) * 64 + l) * 8);
        f32x4 t = {0.f, 0.f, 0.f, 0.f};
        t = __builtin_amdgcn_mfma_f32_16x16x32_bf16(b0, af0, t, 0, 0, 0);
        t = __builtin_amdgcn_mfma_f32_16x16x32_bf16(b1, af1, t, 0, 0, 0);
        ushort4 ub;
        ub.x = f2bf(t[0]); ub.y = f2bf(t[1]); ub.z = f2bf(t[2]); ub.w = f2bf(t[3]);
        *reinterpret_cast<ushort4*>(&bounce[r16][4 * (32 * w + 4 * i + g)]) = ub;
      }
      __syncthreads();
      if (MODE == 1) {                      // bf16 dump: 4 sweeps x 16B/thread
        #pragma unroll
        for (int s = 0; s < 4; ++s) {
          int u = s * 256 + tid;
          int r = u >> 6, cu = u & 63;
          bf16x8 v = *reinterpret_cast<const bf16x8*>(&bounce[r][8 * cu]);
          *reinterpret_cast<bf16x8*>(upb + (size_t)(row0 + r) * QDIM + 512 * p + 8 * cu) = v;
        }
      } else {                              // f32 dump into out: 8 sweeps
        #pragma unroll
        for (int s = 0; s < 8; ++s) {
          int u = s * 256 + tid;
          int r = u >> 7, cu = u & 127;
          ushort4 uv = *reinterpret_cast<const ushort4*>(&bounce[r][4 * cu]);
          float4 o;
          o.x = bf2f(uv.x); o.y = bf2f(uv.y); o.z = bf2f(uv.z); o.w = bf2f(uv.w);
          *reinterpret_cast<float4*>(outg + (size_t)(row0 + r) * QDIM + 512 * p + 4 * cu) = o;
        }
      }
    }
  }
}

// ---- Pure streaming adds (m13-style: grid-stride, no LDS, tiny VGPR).
__global__ __launch_bounds__(256)
void k_add_bf16(const ushort* __restrict__ upb, const float* __restrict__ resg,
                float* __restrict__ outg) {
  size_t base = (size_t)blockIdx.x * 256 + threadIdx.x;
  #pragma unroll 4
  for (int k = 0; k < 16; ++k) {
    size_t i4 = base + (size_t)k * 524288;     // float4-unit index
    ushort4 uv = *reinterpret_cast<const ushort4*>(upb + 4 * i4);
    f32x4 rv = *reinterpret_cast<const f32x4*>(resg + 4 * i4);
    f32x4 o;
    o[0] = rv[0] + bf2f(uv.x); o[1] = rv[1] + bf2f(uv.y);
    o[2] = rv[2] + bf2f(uv.z); o[3] = rv[3] + bf2f(uv.w);
    *reinterpret_cast<f32x4*>(outg + 4 * i4) = o;
  }
}

__global__ __launch_bounds__(256)
void k_add_f32(const float* __restrict__ resg, float* __restrict__ outg) {
  size_t base = (size_t)blockIdx.x * 256 + threadIdx.x;
  #pragma unroll 4
  for (int k = 0; k < 16; ++k) {
    size_t i4 = base + (size_t)k * 524288;
    f32x4 ov = *reinterpret_cast<const f32x4*>(outg + 4 * i4);   // up (f32, staged)
    f32x4 rv = *reinterpret_cast<const f32x4*>(resg + 4 * i4);
    f32x4 o = ov + rv;                                           // same-thread RMW
    *reinterpret_cast<f32x4*>(outg + 4 * i4) = o;
  }
}

extern "C" void kernel_launch(void* const* d_in, const int* in_sizes, int n_in,
                              void* d_out, int out_size, void* d_ws, size_t ws_size,
                              hipStream_t stream) {
  (void)in_sizes; (void)n_in; (void)out_size;
  const float* x     = (const float*)d_in[0];
  const float* resid = (const float*)d_in[1];
  const float* Wproj = (const float*)d_in[2];
  const float* Wdown = (const float*)d_in[3];
  const float* gamma = (const float*)d_in[4];
  const float* beta  = (const float*)d_in[5];
  const float* Wl1   = (const float*)d_in[6];
  const float* bl1   = (const float*)d_in[7];
  const float* Wl2   = (const float*)d_in[8];
  const float* bl2   = (const float*)d_in[9];
  const float* Wup   = (const float*)d_in[10];
  float* out = (float*)d_out;

  char* ws = (char*)d_ws;
  float*  part = (float*)(ws);                   // 1,572,864 B
  ushort* wcf  = (ushort*)(ws + 1572864);        //    98,304 B
  ushort* wupf = (ushort*)(ws + 1671168);        //   131,072 B
  ushort* wl1f = (ushort*)(ws + 1802240);        //     8,192 B
  ushort* wl2f = (ushort*)(ws + 1810432);        //     8,192 B
  ushort* upb  = (ushort*)(ws + 1818624);        // 67,108,864 B (if available)
  const size_t NEED = 1818624ull + 67108864ull;

  k_wcomb  <<<768, 64, 0, stream>>>(Wproj, Wdown, part);
  k_arrange<<<480, 256, 0, stream>>>(part, Wup, Wl1, Wl2, wcf, wupf, wl1f, wl2f);
  if (ws_size >= NEED) {
    k_act<1> <<<2048, 256, 0, stream>>>(x, gamma, beta, bl1, bl2,
                                        wcf, wupf, wl1f, wl2f, upb, out);
    k_add_bf16<<<2048, 256, 0, stream>>>(upb, resid, out);
  } else {
    k_act<0> <<<2048, 256, 0, stream>>>(x, gamma, beta, bl1, bl2,
                                        wcf, wupf, wl1f, wl2f, nullptr, out);
    k_add_f32<<<2048, 256, 0, stream>>>(resid, out);
  }
}

// Round 11
// 129.393 us; speedup vs baseline: 1.1492x; 1.1492x over previous
//
#include <hip/hip_runtime.h>

// BottleneckAdapter: out = residual + Wup·( swish(Wl1·n+bl1) * (Wl2·n+bl2) ),
// n = LN( (Wdown·Wproj)·x ).  W_comb = Wdown@Wproj precomputed per-launch.
// Dims: B=16 S=2048 C=768 Q=1024 D=64 -> ROWS=32768.
//
// R11: fused k_main, minimal traffic (x+res+out only), res fully DMA-prefetched:
//  - res half-0 (cols 0-511, 32KB) DMA'd at cycle 0 -> lands under phases A-D.
//  - res half-1 DMA'd post-D into the dead x/d/n region -> lands under pass 0.
//  - epilogue = 2 passes of {wupf L2 loads, MFMA, res from LDS, fused store}.
//  - waits: phase-A __syncthreads (res0 already due) and robust vmcnt(8)
//    (in-order retirement => DMAs retired even if spills add vm ops) + raw
//    s_barrier before pass 1. LDS = 64KB exactly -> 2 blocks/CU.
//  - res LDS layout: quad p of row r holds logical quad p^(r&7) (swizzle done
//    on the DMA SOURCE address; dest linear as global_load_lds requires).

#define CDIM 768
#define QDIM 1024

typedef __attribute__((ext_vector_type(8))) short bf16x8;
typedef __attribute__((ext_vector_type(4))) float f32x4;

#define SCHED0() __builtin_amdgcn_sched_barrier(0)

__device__ __forceinline__ ushort f2bf(float f) {
  union { float f; unsigned u; } v; v.f = f;
  unsigned r = v.u + 0x7fffu + ((v.u >> 16) & 1u);   // RNE
  return (ushort)(r >> 16);
}

__device__ __forceinline__ void gload16(const float* g, void* lds) {
  __builtin_amdgcn_global_load_lds(
      (const __attribute__((address_space(1))) void*)g,
      (__attribute__((address_space(3))) void*)lds, 16, 0, 0);
}

// ---- K1: partial W_comb, 8 q-chunks. part[qc][c][d] (8 x 768 x 64 f32)
__global__ void k_wcomb(const float* __restrict__ Wproj, const float* __restrict__ Wdown,
                        float* __restrict__ part) {
  int bid = blockIdx.x;                 // 768 = 12 cb * 8 db * 8 qc
  int cb = bid % 12, db = (bid / 12) % 8, qc = bid / 96;
  int l = threadIdx.x;                  // 64
  int c = cb * 64 + l;
  float acc[8];
  #pragma unroll
  for (int i = 0; i < 8; ++i) acc[i] = 0.f;
  int q0 = qc * 128;
  for (int q = q0; q < q0 + 128; ++q) {
    float xp = Wproj[q * CDIM + c];
    #pragma unroll
    for (int i = 0; i < 8; ++i)
      acc[i] = fmaf(Wdown[(db * 8 + i) * QDIM + q], xp, acc[i]);
  }
  #pragma unroll
  for (int i = 0; i < 8; ++i)
    part[((size_t)qc * CDIM + c) * 64 + db * 8 + i] = acc[i];
}

// ---- K2: sum partials + arrange weights into MFMA fragment order (bf16).
// element (lane l, j) of tile (ks,nf) = M[16*nf+(l&15)][32*ks + 8*(l>>4)+j]
__global__ void k_arrange(const float* __restrict__ part, const float* __restrict__ Wup,
                          const float* __restrict__ Wl1, const float* __restrict__ Wl2,
                          ushort* __restrict__ wcf, ushort* __restrict__ wupf,
                          ushort* __restrict__ wl1f, ushort* __restrict__ wl2f) {
  int idx = blockIdx.x * 256 + threadIdx.x;      // 480*256 = 122880
  if (idx < 49152) {                             // wcf
    int i0 = idx;
    int j = i0 & 7, l = (i0 >> 3) & 63, t = i0 >> 9;
    int g = l >> 4, r16 = l & 15;
    int nf = t & 3, ks = t >> 2;
    int k = 32 * ks + 8 * g + j, n = 16 * nf + r16;
    float s = 0.f;
    #pragma unroll
    for (int qc = 0; qc < 8; ++qc) s += part[((size_t)qc * CDIM + k) * 64 + n];
    wcf[i0] = f2bf(s);
  } else if (idx < 49152 + 65536) {              // wupf
    int i2 = idx - 49152;
    int j = i2 & 7, l = (i2 >> 3) & 63, t = i2 >> 9;
    int g = l >> 4, r16 = l & 15;
    int ks = t & 1, nf = t >> 1;
    int k = 32 * ks + 8 * g + j, n = 16 * nf + r16;
    wupf[i2] = f2bf(Wup[n * 64 + k]);
  } else if (idx < 49152 + 65536 + 4096) {       // wl1f
    int i3 = idx - (49152 + 65536);
    int j = i3 & 7, l = (i3 >> 3) & 63, t = i3 >> 9;
    int g = l >> 4, r16 = l & 15;
    int nf = t & 3, ks = t >> 2;
    int k = 32 * ks + 8 * g + j, e = 16 * nf + r16;
    wl1f[i3] = f2bf(Wl1[e * 64 + k]);
  } else {                                       // wl2f
    int i4 = idx - (49152 + 65536 + 4096);
    int j = i4 & 7, l = (i4 >> 3) & 63, t = i4 >> 9;
    int g = l >> 4, r16 = l & 15;
    int nf = t & 3, ks = t >> 2;
    int k = 32 * ks + 8 * g + j, e = 16 * nf + r16;
    wl2f[i4] = f2bf(Wl2[e * 64 + k]);
  }
}

// ---- K_MAIN. 2048 blocks x 256 thr, LDS 64KB -> 2 blocks/CU.
// LDS map (bytes):
//   @0     x[16][776]us (24832)  phases A/B       \
//   @24832 d[16][68]f32 (4352)   B->C; a[16][72]us (2304) in D (d dead)
//   @29184 n[16][72]us  (2304)   C->D              | r1 = res half-1 @0..32768
//   @32768 r0 = res half-0 f32 [16][512] (32768)   (DMA'd post-D, all dead)
template<int DUMMY>
__global__ __launch_bounds__(256, 2)
void k_main(const float* __restrict__ xg, const float* __restrict__ resg,
            const float* __restrict__ gamma, const float* __restrict__ beta,
            const float* __restrict__ bl1, const float* __restrict__ bl2,
            const ushort* __restrict__ wcf, const ushort* __restrict__ wupf,
            const ushort* __restrict__ wl1f, const ushort* __restrict__ wl2f,
            float* __restrict__ outg) {
  __shared__ alignas(16) char smem[65536];
  ushort (*x_lds)[776] = reinterpret_cast<ushort(*)[776]>(smem);
  float  (*d_lds)[68]  = reinterpret_cast<float (*)[68]>(smem + 24832);
  ushort (*a_lds)[72]  = reinterpret_cast<ushort(*)[72]>(smem + 24832);
  ushort (*n_lds)[72]  = reinterpret_cast<ushort(*)[72]>(smem + 29184);
  float* r1 = reinterpret_cast<float*>(smem);            // pass-1 res
  float* r0 = reinterpret_cast<float*>(smem + 32768);    // pass-0 res

  const int tid = threadIdx.x;
  const int w = tid >> 6, l = tid & 63, g = l >> 4, r16 = l & 15;
  const int row0 = blockIdx.x * 16;
  const size_t rrow = (size_t)row0 * QDIM;

  // Prologue: DMA res half-0 (cols 0-511) -> r0. 8 sweeps x 4KB.
  // Source pre-swizzled: phys quad p of row r <- logical quad p^(r&7).
  #pragma unroll
  for (int s = 0; s < 8; ++s) {
    int G = s * 256 + tid;
    int r = G >> 7, p = G & 127;
    gload16(resg + rrow + (size_t)r * QDIM + 4 * (p ^ (r & 7)),
            smem + 32768 + (size_t)(s * 256 + w * 64) * 16);
  }
  SCHED0();

  // Phase A: stage x (16x768 f32) -> LDS bf16, float4 coalesced.
  #pragma unroll
  for (int i = 0; i < 12; ++i) {
    int f4 = i * 256 + tid;
    int r = f4 / 192;
    int c4 = (f4 - r * 192) * 4;
    const float4 v = *reinterpret_cast<const float4*>(xg + (size_t)(row0 + r) * CDIM + c4);
    ushort4 b;
    b.x = f2bf(v.x); b.y = f2bf(v.y); b.z = f2bf(v.z); b.w = f2bf(v.w);
    *reinterpret_cast<ushort4*>(&x_lds[r][c4]) = b;
  }
  __syncthreads();   // drains vmcnt(0): x AND res0 ready, all waves synced

  // Phase B: d = x * Wcomb^T. (d region is outside x -> no extra barrier)
  f32x4 dacc = {0.f, 0.f, 0.f, 0.f};
  #pragma unroll 8
  for (int ks = 0; ks < 24; ++ks) {
    bf16x8 a = *reinterpret_cast<const bf16x8*>(&x_lds[r16][ks * 32 + 8 * g]);
    bf16x8 b = *reinterpret_cast<const bf16x8*>(wcf + ((size_t)(ks * 4 + w) * 64 + l) * 8);
    dacc = __builtin_amdgcn_mfma_f32_16x16x32_bf16(a, b, dacc, 0, 0, 0);
  }
  #pragma unroll
  for (int rg = 0; rg < 4; ++rg) d_lds[4 * g + rg][16 * w + r16] = dacc[rg];
  __syncthreads();

  // Phase C: LayerNorm over D=64.
  {
    int row = 4 * w + g;
    f32x4 v = *reinterpret_cast<const f32x4*>(&d_lds[row][4 * r16]);
    float s  = v[0] + v[1] + v[2] + v[3];
    float sq = v[0]*v[0] + v[1]*v[1] + v[2]*v[2] + v[3]*v[3];
    #pragma unroll
    for (int m = 1; m < 16; m <<= 1) {
      s  += __shfl_xor(s, m, 64);
      sq += __shfl_xor(sq, m, 64);
    }
    float mu  = s * (1.f / 64.f);
    float var = sq * (1.f / 64.f) - mu * mu;
    float rs  = rsqrtf(var + 1e-5f);
    const float4 gm = *reinterpret_cast<const float4*>(gamma + 4 * r16);
    const float4 bt = *reinterpret_cast<const float4*>(beta  + 4 * r16);
    ushort4 nb;
    nb.x = f2bf((v[0] - mu) * rs * gm.x + bt.x);
    nb.y = f2bf((v[1] - mu) * rs * gm.y + bt.y);
    nb.z = f2bf((v[2] - mu) * rs * gm.z + bt.z);
    nb.w = f2bf((v[3] - mu) * rs * gm.w + bt.w);
    *reinterpret_cast<ushort4*>(&n_lds[row][4 * r16]) = nb;
  }
  __syncthreads();   // d dead from here -> a_lds may reuse its region

  // Phase D: SwiGLU -> a_lds (@24832, old d region).
  {
    bf16x8 a0 = *reinterpret_cast<const bf16x8*>(&n_lds[r16][8 * g]);
    bf16x8 a1 = *reinterpret_cast<const bf16x8*>(&n_lds[r16][32 + 8 * g]);
    bf16x8 b10 = *reinterpret_cast<const bf16x8*>(wl1f + ((size_t)(0 * 4 + w) * 64 + l) * 8);
    bf16x8 b11 = *reinterpret_cast<const bf16x8*>(wl1f + ((size_t)(1 * 4 + w) * 64 + l) * 8);
    bf16x8 b20 = *reinterpret_cast<const bf16x8*>(wl2f + ((size_t)(0 * 4 + w) * 64 + l) * 8);
    bf16x8 b21 = *reinterpret_cast<const bf16x8*>(wl2f + ((size_t)(1 * 4 + w) * 64 + l) * 8);
    f32x4 z = {0.f, 0.f, 0.f, 0.f};
    f32x4 acc1 = __builtin_amdgcn_mfma_f32_16x16x32_bf16(a0, b10, z, 0, 0, 0);
    acc1 = __builtin_amdgcn_mfma_f32_16x16x32_bf16(a1, b11, acc1, 0, 0, 0);
    f32x4 acc2 = __builtin_amdgcn_mfma_f32_16x16x32_bf16(a0, b20, z, 0, 0, 0);
    acc2 = __builtin_amdgcn_mfma_f32_16x16x32_bf16(a1, b21, acc2, 0, 0, 0);
    float bv1 = bl1[16 * w + r16];
    float bv2 = bl2[16 * w + r16];
    #pragma unroll
    for (int rg = 0; rg < 4; ++rg) {
      float o1 = acc1[rg] + bv1;
      float o2 = acc2[rg] + bv2;
      float sw = o1 / (1.f + __expf(-o1));       // swish
      a_lds[4 * g + rg][16 * w + r16] = f2bf(sw * o2);
    }
  }
  __syncthreads();

  // Hoist a-fragments to registers (a_lds lives inside the r1 DMA target).
  const bf16x8 af0 = *reinterpret_cast<const bf16x8*>(&a_lds[r16][8 * g]);
  const bf16x8 af1 = *reinterpret_cast<const bf16x8*>(&a_lds[r16][32 + 8 * g]);
  asm volatile("s_waitcnt lgkmcnt(0)" ::: "memory");
  SCHED0();
  __builtin_amdgcn_s_barrier();      // all waves hold af in regs before r1 lands
  SCHED0();

  // DMA res half-1 (cols 512-1023) -> r1 (@0, over dead x/a/n).
  #pragma unroll
  for (int s = 0; s < 8; ++s) {
    int G = s * 256 + tid;
    int r = G >> 7, p = G & 127;
    gload16(resg + rrow + (size_t)r * QDIM + 512 + 4 * (p ^ (r & 7)),
            smem + (size_t)(s * 256 + w * 64) * 16);
  }
  SCHED0();

  // Epilogue pass 0: cols 0-511 (nf = 8w+i), res from r0 (landed long ago).
  {
    float* obase = outg + rrow + (size_t)r16 * QDIM + 128 * w + 4 * g;
    const float* rb = r0 + r16 * 512;
    #pragma unroll
    for (int i = 0; i < 8; ++i) {
      size_t nf = 8 * w + i;
      bf16x8 b0 = *reinterpret_cast<const bf16x8*>(wupf + ((nf * 2 + 0) * 64 + l) * 8);
      bf16x8 b1 = *reinterpret_cast<const bf16x8*>(wupf + ((nf * 2 + 1) * 64 + l) * 8);
      f32x4 t = {0.f, 0.f, 0.f, 0.f};
      t = __builtin_amdgcn_mfma_f32_16x16x32_bf16(b0, af0, t, 0, 0, 0);
      t = __builtin_amdgcn_mfma_f32_16x16x32_bf16(b1, af1, t, 0, 0, 0);
      int p = (32 * w + 4 * i + g) ^ (r16 & 7);
      f32x4 rv = *reinterpret_cast<const f32x4*>(rb + 4 * p);
      *reinterpret_cast<f32x4*>(obase + 16 * i) = rv + t;
    }
  }
  SCHED0();
  // In-order vm retirement: <=8 outstanding => everything older (incl. the 8
  // r1 DMAs, issued 24+ vm-ops ago) has retired. Robust to spill vm-ops.
  asm volatile("s_waitcnt vmcnt(8)" ::: "memory");
  SCHED0();
  __builtin_amdgcn_s_barrier();      // all waves' r1 DMAs retired
  SCHED0();

  // Epilogue pass 1: cols 512-1023 (nf = 32+8w+i), res from r1.
  {
    float* obase = outg + rrow + (size_t)r16 * QDIM + 512 + 128 * w + 4 * g;
    const float* rb = r1 + r16 * 512;
    #pragma unroll
    for (int i = 0; i < 8; ++i) {
      size_t nf = 32 + 8 * w + i;
      bf16x8 b0 = *reinterpret_cast<const bf16x8*>(wupf + ((nf * 2 + 0) * 64 + l) * 8);
      bf16x8 b1 = *reinterpret_cast<const bf16x8*>(wupf + ((nf * 2 + 1) * 64 + l) * 8);
      f32x4 t = {0.f, 0.f, 0.f, 0.f};
      t = __builtin_amdgcn_mfma_f32_16x16x32_bf16(b0, af0, t, 0, 0, 0);
      t = __builtin_amdgcn_mfma_f32_16x16x32_bf16(b1, af1, t, 0, 0, 0);
      int p = (32 * w + 4 * i + g) ^ (r16 & 7);
      f32x4 rv = *reinterpret_cast<const f32x4*>(rb + 4 * p);
      *reinterpret_cast<f32x4*>(obase + 16 * i) = rv + t;
    }
  }
}

extern "C" void kernel_launch(void* const* d_in, const int* in_sizes, int n_in,
                              void* d_out, int out_size, void* d_ws, size_t ws_size,
                              hipStream_t stream) {
  (void)in_sizes; (void)n_in; (void)out_size; (void)ws_size;
  const float* x     = (const float*)d_in[0];
  const float* resid = (const float*)d_in[1];
  const float* Wproj = (const float*)d_in[2];
  const float* Wdown = (const float*)d_in[3];
  const float* gamma = (const float*)d_in[4];
  const float* beta  = (const float*)d_in[5];
  const float* Wl1   = (const float*)d_in[6];
  const float* bl1   = (const float*)d_in[7];
  const float* Wl2   = (const float*)d_in[8];
  const float* bl2   = (const float*)d_in[9];
  const float* Wup   = (const float*)d_in[10];
  float* out = (float*)d_out;

  char* ws = (char*)d_ws;
  float*  part = (float*)(ws);                   // 1,572,864 B
  ushort* wcf  = (ushort*)(ws + 1572864);        //    98,304 B
  ushort* wupf = (ushort*)(ws + 1671168);        //   131,072 B
  ushort* wl1f = (ushort*)(ws + 1802240);        //     8,192 B
  ushort* wl2f = (ushort*)(ws + 1810432);        //     8,192 B

  k_wcomb  <<<768, 64, 0, stream>>>(Wproj, Wdown, part);
  k_arrange<<<480, 256, 0, stream>>>(part, Wup, Wl1, Wl2, wcf, wupf, wl1f, wl2f);
  k_main<0><<<2048, 256, 0, stream>>>(x, resid, gamma, beta, bl1, bl2,
                                      wcf, wupf, wl1f, wl2f, out);
}

// Round 12
// 104.620 us; speedup vs baseline: 1.4213x; 1.2368x over previous
//
#include <hip/hip_runtime.h>

// BottleneckAdapter: out = residual + Wup·( swish(Wl1·n+bl1) * (Wl2·n+bl2) ),
// n = LN( (Wdown·Wproj)·x ).  W_comb = Wdown@Wproj precomputed per-launch.
// Dims: B=16 S=2048 C=768 Q=1024 D=64 -> ROWS=32768.
//
// R12: restore R4's k_up VERBATIM (timed-pass evidence: ~48us, 5.4 TB/s — the
// rocprof counter pass inflated it to 90+ and misled R5-R11). Chain kernel
// k_act reworked to 1024 blocks x 512 thr x 32 rows (8 wave-tasks = 2 row-
// tiles x 4 col-frags) to halve per-block serial overhead, 3 blocks/CU.

#define CDIM 768
#define QDIM 1024

typedef __attribute__((ext_vector_type(8))) short bf16x8;
typedef __attribute__((ext_vector_type(4))) float f32x4;

__device__ __forceinline__ ushort f2bf(float f) {
  union { float f; unsigned u; } v; v.f = f;
  unsigned r = v.u + 0x7fffu + ((v.u >> 16) & 1u);   // RNE
  return (ushort)(r >> 16);
}

__device__ __forceinline__ void gload16(const float* g, float* lds) {
  __builtin_amdgcn_global_load_lds(
      (const __attribute__((address_space(1))) void*)g,
      (__attribute__((address_space(3))) void*)lds, 16, 0, 0);
}

// ---- K1: partial W_comb, 8 q-chunks. part[qc][c][d] (8 x 768 x 64 f32)
__global__ void k_wcomb(const float* __restrict__ Wproj, const float* __restrict__ Wdown,
                        float* __restrict__ part) {
  int bid = blockIdx.x;                 // 768 = 12 cb * 8 db * 8 qc
  int cb = bid % 12, db = (bid / 12) % 8, qc = bid / 96;
  int l = threadIdx.x;                  // 64
  int c = cb * 64 + l;
  float acc[8];
  #pragma unroll
  for (int i = 0; i < 8; ++i) acc[i] = 0.f;
  int q0 = qc * 128;
  for (int q = q0; q < q0 + 128; ++q) {
    float xp = Wproj[q * CDIM + c];
    #pragma unroll
    for (int i = 0; i < 8; ++i)
      acc[i] = fmaf(Wdown[(db * 8 + i) * QDIM + q], xp, acc[i]);
  }
  #pragma unroll
  for (int i = 0; i < 8; ++i)
    part[((size_t)qc * CDIM + c) * 64 + db * 8 + i] = acc[i];
}

// ---- K2: sum partials + arrange weights into MFMA fragment order (bf16).
// element (lane l, j) of tile (ks,nf) = M[16*nf+(l&15)][32*ks + 8*(l>>4)+j]
__global__ void k_arrange(const float* __restrict__ part, const float* __restrict__ Wup,
                          const float* __restrict__ Wl1, const float* __restrict__ Wl2,
                          ushort* __restrict__ wcf, ushort* __restrict__ wupf,
                          ushort* __restrict__ wl1f, ushort* __restrict__ wl2f) {
  int idx = blockIdx.x * 256 + threadIdx.x;      // 480*256 = 122880
  if (idx < 49152) {                             // wcf
    int i0 = idx;
    int j = i0 & 7, l = (i0 >> 3) & 63, t = i0 >> 9;
    int g = l >> 4, r16 = l & 15;
    int nf = t & 3, ks = t >> 2;
    int k = 32 * ks + 8 * g + j, n = 16 * nf + r16;
    float s = 0.f;
    #pragma unroll
    for (int qc = 0; qc < 8; ++qc) s += part[((size_t)qc * CDIM + k) * 64 + n];
    wcf[i0] = f2bf(s);
  } else if (idx < 49152 + 65536) {              // wupf
    int i2 = idx - 49152;
    int j = i2 & 7, l = (i2 >> 3) & 63, t = i2 >> 9;
    int g = l >> 4, r16 = l & 15;
    int ks = t & 1, nf = t >> 1;
    int k = 32 * ks + 8 * g + j, n = 16 * nf + r16;
    wupf[i2] = f2bf(Wup[n * 64 + k]);
  } else if (idx < 49152 + 65536 + 4096) {       // wl1f
    int i3 = idx - (49152 + 65536);
    int j = i3 & 7, l = (i3 >> 3) & 63, t = i3 >> 9;
    int g = l >> 4, r16 = l & 15;
    int nf = t & 3, ks = t >> 2;
    int k = 32 * ks + 8 * g + j, e = 16 * nf + r16;
    wl1f[i3] = f2bf(Wl1[e * 64 + k]);
  } else {                                       // wl2f
    int i4 = idx - (49152 + 65536 + 4096);
    int j = i4 & 7, l = (i4 >> 3) & 63, t = i4 >> 9;
    int g = l >> 4, r16 = l & 15;
    int nf = t & 3, ks = t >> 2;
    int k = 32 * ks + 8 * g + j, e = 16 * nf + r16;
    wl2f[i4] = f2bf(Wl2[e * 64 + k]);
  }
}

// ---- K_A: x -> down -> LN -> SwiGLU -> a[] (bf16).
// 1024 blocks x 512 thr, 32 rows/block, 8 wave-tasks (rt=w>>2, fc=w&3).
// LDS 49664B: x[32][776]us full | d[32][68]f32 @0 | n[32][72]us @8704 |
//             a[32][72]us @13312  (all within dead-x region after extra barrier)
__global__ __launch_bounds__(512, 3)
void k_act(const float* __restrict__ xg,
           const float* __restrict__ gamma, const float* __restrict__ beta,
           const float* __restrict__ bl1, const float* __restrict__ bl2,
           const ushort* __restrict__ wcf,
           const ushort* __restrict__ wl1f, const ushort* __restrict__ wl2f,
           ushort* __restrict__ ag) {
  __shared__ alignas(16) ushort smem[24832];     // 49664 B
  ushort (*x_lds)[776] = reinterpret_cast<ushort(*)[776]>(smem);
  float  (*d_lds)[68]  = reinterpret_cast<float (*)[68]>(smem);
  ushort (*n_lds)[72]  = reinterpret_cast<ushort(*)[72]>(reinterpret_cast<char*>(smem) + 8704);
  ushort (*a_lds)[72]  = reinterpret_cast<ushort(*)[72]>(reinterpret_cast<char*>(smem) + 13312);

  const int tid = threadIdx.x;
  const int w = tid >> 6, l = tid & 63, g = l >> 4, r16 = l & 15;
  const int rt = w >> 2, fc = w & 3;             // row-tile, col-frag
  const int row0 = blockIdx.x * 32;

  // Phase A: stage x (32x768 f32) -> LDS bf16. 12 float4/thread, coalesced.
  #pragma unroll
  for (int i = 0; i < 12; ++i) {
    int f4 = i * 512 + tid;                    // 0..6143
    int r = f4 / 192;
    int c4 = (f4 - r * 192) * 4;
    const float4 v = *reinterpret_cast<const float4*>(xg + (size_t)(row0 + r) * CDIM + c4);
    ushort4 b;
    b.x = f2bf(v.x); b.y = f2bf(v.y); b.z = f2bf(v.z); b.w = f2bf(v.w);
    *reinterpret_cast<ushort4*>(&x_lds[r][c4]) = b;
  }
  __syncthreads();

  // Phase B: d(32x64) = x * Wcomb^T. Wave w: rows 16rt.., cols 16fc..
  f32x4 dacc = {0.f, 0.f, 0.f, 0.f};
  #pragma unroll 8
  for (int ks = 0; ks < 24; ++ks) {
    bf16x8 a = *reinterpret_cast<const bf16x8*>(&x_lds[16 * rt + r16][ks * 32 + 8 * g]);
    bf16x8 b = *reinterpret_cast<const bf16x8*>(wcf + ((size_t)(ks * 4 + fc) * 64 + l) * 8);
    dacc = __builtin_amdgcn_mfma_f32_16x16x32_bf16(a, b, dacc, 0, 0, 0);
  }
  __syncthreads();                             // all x reads done before overwrite
  #pragma unroll
  for (int rg = 0; rg < 4; ++rg)
    d_lds[16 * rt + 4 * g + rg][16 * fc + r16] = dacc[rg];
  __syncthreads();

  // Phase C: LayerNorm over D=64. Wave w rows 4w..4w+3 (w=0..7 covers 0..31).
  {
    int row = 4 * w + g;
    f32x4 v = *reinterpret_cast<const f32x4*>(&d_lds[row][4 * r16]);
    float s  = v[0] + v[1] + v[2] + v[3];
    float sq = v[0]*v[0] + v[1]*v[1] + v[2]*v[2] + v[3]*v[3];
    #pragma unroll
    for (int m = 1; m < 16; m <<= 1) {
      s  += __shfl_xor(s, m, 64);
      sq += __shfl_xor(sq, m, 64);
    }
    float mu  = s * (1.f / 64.f);
    float var = sq * (1.f / 64.f) - mu * mu;
    float rs  = rsqrtf(var + 1e-5f);
    const float4 gm = *reinterpret_cast<const float4*>(gamma + 4 * r16);
    const float4 bt = *reinterpret_cast<const float4*>(beta  + 4 * r16);
    ushort4 nb;
    nb.x = f2bf((v[0] - mu) * rs * gm.x + bt.x);
    nb.y = f2bf((v[1] - mu) * rs * gm.y + bt.y);
    nb.z = f2bf((v[2] - mu) * rs * gm.z + bt.z);
    nb.w = f2bf((v[3] - mu) * rs * gm.w + bt.w);
    *reinterpret_cast<ushort4*>(&n_lds[row][4 * r16]) = nb;
  }
  __syncthreads();

  // Phase D: SwiGLU. Wave w: rows 16rt.., cols 16fc.. -> a_lds.
  {
    bf16x8 a0 = *reinterpret_cast<const bf16x8*>(&n_lds[16 * rt + r16][8 * g]);
    bf16x8 a1 = *reinterpret_cast<const bf16x8*>(&n_lds[16 * rt + r16][32 + 8 * g]);
    bf16x8 b10 = *reinterpret_cast<const bf16x8*>(wl1f + ((size_t)(0 * 4 + fc) * 64 + l) * 8);
    bf16x8 b11 = *reinterpret_cast<const bf16x8*>(wl1f + ((size_t)(1 * 4 + fc) * 64 + l) * 8);
    bf16x8 b20 = *reinterpret_cast<const bf16x8*>(wl2f + ((size_t)(0 * 4 + fc) * 64 + l) * 8);
    bf16x8 b21 = *reinterpret_cast<const bf16x8*>(wl2f + ((size_t)(1 * 4 + fc) * 64 + l) * 8);
    f32x4 z = {0.f, 0.f, 0.f, 0.f};
    f32x4 acc1 = __builtin_amdgcn_mfma_f32_16x16x32_bf16(a0, b10, z, 0, 0, 0);
    acc1 = __builtin_amdgcn_mfma_f32_16x16x32_bf16(a1, b11, acc1, 0, 0, 0);
    f32x4 acc2 = __builtin_amdgcn_mfma_f32_16x16x32_bf16(a0, b20, z, 0, 0, 0);
    acc2 = __builtin_amdgcn_mfma_f32_16x16x32_bf16(a1, b21, acc2, 0, 0, 0);
    float bv1 = bl1[16 * fc + r16];
    float bv2 = bl2[16 * fc + r16];
    #pragma unroll
    for (int rg = 0; rg < 4; ++rg) {
      float o1 = acc1[rg] + bv1;
      float o2 = acc2[rg] + bv2;
      float sw = o1 / (1.f + __expf(-o1));       // swish
      a_lds[16 * rt + 4 * g + rg][16 * fc + r16] = f2bf(sw * o2);
    }
  }
  __syncthreads();

  // Contiguous ag dump: 256 threads x 16B = 4KB.
  if (tid < 256) {
    int r = tid >> 3, c = 8 * (tid & 7);
    bf16x8 v = *reinterpret_cast<const bf16x8*>(&a_lds[r][c]);
    *reinterpret_cast<bf16x8*>(ag + (size_t)(row0 + r) * 64 + c) = v;
  }
}

// ---- K_B: out = res + a * Wup^T.  R4-VERBATIM DMA-pipelined streaming kernel.
// Lane l (wave w): out-row = l&15, out-cols 16*(16w+nfl)+4*(l>>4)+{0..3}.
__global__ __launch_bounds__(256, 2)
void k_up(const ushort* __restrict__ ag, const float* __restrict__ resg,
          const ushort* __restrict__ wupf, float* __restrict__ outg) {
  __shared__ float res_lds[4][16][256];   // exactly 64 KiB, wave-private slices
  const int tid = threadIdx.x;
  const int w = tid >> 6, l = tid & 63, g = l >> 4, r16 = l & 15;
  const int row0 = blockIdx.x * 16;

  // a-fragments straight from global (2KB tile)
  const bf16x8 af0 = *reinterpret_cast<const bf16x8*>(ag + (size_t)(row0 + r16) * 64 + 8 * g);
  const bf16x8 af1 = *reinterpret_cast<const bf16x8*>(ag + (size_t)(row0 + r16) * 64 + 32 + 8 * g);

  // Product first: acc[nfl]; all wupf loads older than the DMAs below.
  f32x4 acc[16];
  #pragma unroll
  for (int nfl = 0; nfl < 16; ++nfl) {
    int nf = 16 * w + nfl;
    bf16x8 b0 = *reinterpret_cast<const bf16x8*>(wupf + ((size_t)(nf * 2 + 0) * 64 + l) * 8);
    bf16x8 b1 = *reinterpret_cast<const bf16x8*>(wupf + ((size_t)(nf * 2 + 1) * 64 + l) * 8);
    f32x4 t = {0.f, 0.f, 0.f, 0.f};
    t = __builtin_amdgcn_mfma_f32_16x16x32_bf16(b0, af0, t, 0, 0, 0);
    acc[nfl] = __builtin_amdgcn_mfma_f32_16x16x32_bf16(b1, af1, t, 0, 0, 0);
  }
  __builtin_amdgcn_sched_barrier(0);   // keep DMAs after all wupf/MFMA

  // res DMA: 16 rows x 1KB into this wave's slice. Row i rotated by i quads
  // on the SOURCE side (dest linear as global_load_lds requires).
  #pragma unroll
  for (int i = 0; i < 16; ++i) {
    const float* gsrc = resg + (size_t)(row0 + i) * QDIM + 256 * w + 4 * ((l + i) & 63);
    gload16(gsrc, &res_lds[w][i][0]);
  }
  asm volatile("s_waitcnt vmcnt(0)" ::: "memory");
  __builtin_amdgcn_sched_barrier(0);
  // no __syncthreads: each wave reads only its own slice

  // add + nontemporal store
  #pragma unroll
  for (int nfl = 0; nfl < 16; ++nfl) {
    int qr = (4 * nfl + g - r16) & 63;         // undo source rotation of row r16
    const f32x4 rv = *reinterpret_cast<const f32x4*>(&res_lds[w][r16][4 * qr]);
    f32x4 o = rv + acc[nfl];
    f32x4* dst = reinterpret_cast<f32x4*>(
        outg + (size_t)(row0 + r16) * QDIM + 16 * (16 * w + nfl) + 4 * g);
    __builtin_nontemporal_store(o, dst);
  }
}

extern "C" void kernel_launch(void* const* d_in, const int* in_sizes, int n_in,
                              void* d_out, int out_size, void* d_ws, size_t ws_size,
                              hipStream_t stream) {
  (void)in_sizes; (void)n_in; (void)out_size; (void)ws_size;
  const float* x     = (const float*)d_in[0];
  const float* resid = (const float*)d_in[1];
  const float* Wproj = (const float*)d_in[2];
  const float* Wdown = (const float*)d_in[3];
  const float* gamma = (const float*)d_in[4];
  const float* beta  = (const float*)d_in[5];
  const float* Wl1   = (const float*)d_in[6];
  const float* bl1   = (const float*)d_in[7];
  const float* Wl2   = (const float*)d_in[8];
  const float* bl2   = (const float*)d_in[9];
  const float* Wup   = (const float*)d_in[10];
  float* out = (float*)d_out;

  char* ws = (char*)d_ws;
  float*  part = (float*)(ws);                   // 1,572,864 B
  ushort* wcf  = (ushort*)(ws + 1572864);        //    98,304 B
  ushort* wupf = (ushort*)(ws + 1671168);        //   131,072 B
  ushort* wl1f = (ushort*)(ws + 1802240);        //     8,192 B
  ushort* wl2f = (ushort*)(ws + 1810432);        //     8,192 B
  ushort* ag   = (ushort*)(ws + 1818624);        // 4,194,304 B

  k_wcomb  <<<768, 64, 0, stream>>>(Wproj, Wdown, part);
  k_arrange<<<480, 256, 0, stream>>>(part, Wup, Wl1, Wl2, wcf, wupf, wl1f, wl2f);
  k_act    <<<1024, 512, 0, stream>>>(x, gamma, beta, bl1, bl2, wcf, wl1f, wl2f, ag);
  k_up     <<<2048, 256, 0, stream>>>(ag, resid, wupf, out);
}